// Round 16
// baseline (279.841 us; speedup 1.0000x reference)
//
#include <hip/hip_runtime.h>
#include <cmath>

#define Bq 64
#define Qn 900
#define Tn 100
#define Cn 92
#define INFN 1e9f
#define QT 32         // queries per cost tile
#define NQT 29        // ceil(900/32)

// ---- monotonic float<->uint key (bit-exact involution pair) ----
__device__ inline unsigned fkey(float x) {
    unsigned u = __float_as_uint(x);
    return (u & 0x80000000u) ? ~u : (u | 0x80000000u);
}
__device__ inline float unfkey(unsigned k) {
    unsigned u = (k & 0x80000000u) ? (k & 0x7FFFFFFFu) : ~k;
    return __uint_as_float(u);
}

// ---- wave64 min-reduce via DPP (rocPRIM pattern), broadcast from lane 63 ----
__device__ inline unsigned wave_min_u32(unsigned x) {
    unsigned t;
#define DPPSTEP(ctrl)                                                          \
    t = (unsigned)__builtin_amdgcn_update_dpp((int)0xFFFFFFFF, (int)x, ctrl,   \
                                              0xF, 0xF, false);                \
    x = (t < x) ? t : x;
    DPPSTEP(0x111)   // row_shr:1
    DPPSTEP(0x112)   // row_shr:2
    DPPSTEP(0x114)   // row_shr:4
    DPPSTEP(0x118)   // row_shr:8
    DPPSTEP(0x142)   // row_bcast:15
    DPPSTEP(0x143)   // row_bcast:31
#undef DPPSTEP
    return (unsigned)__builtin_amdgcn_readlane((int)x, 63);
}

// ---------------- Fused kernel: cost + transpose + JV, one block per batch ----
// Block b: (1) tile loop computes cost [Q,T] (written to out) and costT [T,Q]
// (written to ws — stays hot in this XCD's L2 for phase C), accumulating row
// minima in registers; (2) greedy argmin assignment; (3) lazy-dual Dijkstra
// searches (R12 machinery; v starts 0 and only decreases — rectangular dual
// feasibility v_j <= 0, the R9 lesson). No inter-kernel barrier: each block's
// jv starts right after ITS cost slab, and its costT reads are L2-hits.
__global__ __launch_bounds__(256) void fused_kernel(
        const float* __restrict__ logits,      // [B,Q,C]
        const float* __restrict__ pred_bbox,   // [B,Q,4]
        const int*   __restrict__ tgt_labels,  // [B,T]
        const float* __restrict__ tgt_bbox,    // [B,T,4]
        float* __restrict__ out,               // full d_out
        float* __restrict__ costT)             // [B,T,Q] workspace
{
    const int b    = blockIdx.x;
    const int tid  = threadIdx.x;
    const int lane = tid & 63;
    const int wv   = tid >> 6;

    __shared__ float prob[QT * Cn];      // 11.8 KB
    __shared__ float pb_s[QT][4];
    __shared__ float tb_s[Tn][4];
    __shared__ int   lab_s[Tn];
    __shared__ float ctile[QT][Tn + 1];  // 12.9 KB
    __shared__ int   p0_lds[1024];       // owner of 0-based col (0=free)
    __shared__ int   way_lds[1024];      // swizzled: col c at (c&15)<<6 | c>>4
    __shared__ float u_lds[Tn + 1];
    __shared__ int   amin_lds[Tn];
    __shared__ unsigned char asg[Tn];
    __shared__ int   freelist[Tn];
    __shared__ int   nfree_s;
    __shared__ int   qarr[Tn];

    for (int j = tid; j < 1024; j += 256) p0_lds[j] = 0;
    if (tid == 0) nfree_s = 0;
    if (tid < Tn) {
        *(float4*)tb_s[tid] = *(const float4*)(tgt_bbox + ((size_t)b * Tn + tid) * 4);
        lab_s[tid] = tgt_labels[b * Tn + tid];
    }

    float rbv = 3.0e38f; int rbq = 0;    // running row-min (thread tid < Tn)
    const int g = tid >> 3, l8 = tid & 7;

    float* cbw = costT + (size_t)b * Qn * Tn;

    // ---- cost tile loop ----
    for (int t = 0; t < NQT; ++t) {
        const int q0 = t * QT;
        const int nq = (q0 + QT <= Qn) ? QT : (Qn - q0);   // 32, last tile 4

        {   // stage logits tile (float4; (b*900+q0)*92 % 4 == 0 -> aligned)
            const float4* src4 = (const float4*)(logits + ((size_t)b * Qn + q0) * Cn);
            float4* dst4 = (float4*)prob;
            const int n4 = nq * Cn / 4;
            for (int i = tid; i < n4; i += 256) dst4[i] = src4[i];
        }
        if (tid < nq)
            *(float4*)pb_s[tid] = *(const float4*)(pred_bbox + ((size_t)b * Qn + q0 + tid) * 4);
        __syncthreads();

        // softmax per query: 8 lanes per query (unchanged fp order)
        if (g < nq) {
            float mx = -3.0e38f;
            for (int c = l8; c < Cn; c += 8) mx = fmaxf(mx, prob[g * Cn + c]);
            mx = fmaxf(mx, __shfl_xor(mx, 1));
            mx = fmaxf(mx, __shfl_xor(mx, 2));
            mx = fmaxf(mx, __shfl_xor(mx, 4));
            float s = 0.0f;
            for (int c = l8; c < Cn; c += 8) {
                float e = expf(prob[g * Cn + c] - mx);
                prob[g * Cn + c] = e;
                s += e;
            }
            s += __shfl_xor(s, 1);
            s += __shfl_xor(s, 2);
            s += __shfl_xor(s, 4);
            float inv = 1.0f / s;
            for (int c = l8; c < Cn; c += 8) prob[g * Cn + c] *= inv;
        }
        __syncthreads();

        // cost compute: thread (g,l8) owns query g, targets tt = l8+8t
        if (g < nq) {
            const float pcx = pb_s[g][0], pcy = pb_s[g][1],
                        pw  = pb_s[g][2], ph  = pb_s[g][3];
            const float px1 = pcx - 0.5f * pw, py1 = pcy - 0.5f * ph;
            const float px2 = pcx + 0.5f * pw, py2 = pcy + 0.5f * ph;
            const float a1  = (px2 - px1) * (py2 - py1);
            const float* probg = prob + g * Cn;

            #pragma unroll
            for (int tt8 = 0; tt8 < 13; ++tt8) {
                const int tt = l8 + 8 * tt8;
                if (tt < Tn) {
                    float4 tb = *(const float4*)tb_s[tt];
                    const float tcx = tb.x, tcy = tb.y, tw = tb.z, th = tb.w;

                    float cclass = -probg[lab_s[tt]];
                    float cbbox  = fabsf(pcx - tcx) + fabsf(pcy - tcy)
                                 + fabsf(pw - tw)  + fabsf(ph - th);

                    float tx1 = tcx - 0.5f * tw, ty1 = tcy - 0.5f * th;
                    float tx2 = tcx + 0.5f * tw, ty2 = tcy + 0.5f * th;

                    float a2 = (tx2 - tx1) * (ty2 - ty1);
                    float iw = fmaxf(fminf(px2, tx2) - fmaxf(px1, tx1), 0.0f);
                    float ih = fmaxf(fminf(py2, ty2) - fmaxf(py1, ty1), 0.0f);
                    float inter = iw * ih;
                    float uni = a1 + a2 - inter;
                    float iou = inter / uni;
                    float ew = fmaxf(fmaxf(px2, tx2) - fminf(px1, tx1), 0.0f);
                    float eh = fmaxf(fmaxf(py2, ty2) - fminf(py1, ty1), 0.0f);
                    float ae = ew * eh;
                    ctile[g][tt] = cbbox + cclass - (iou - (ae - uni) / ae);
                }
            }
        }
        __syncthreads();

        {   // flat coalesced cost write (incremental q/tt: no divisions)
            float* cdst = out + (size_t)b * Qn * Tn + (size_t)q0 * Tn;
            int qq = tid / Tn, tt2 = tid - qq * Tn;
            const int total = nq * Tn;
            for (int e = tid; e < total; e += 256) {
                cdst[e] = ctile[qq][tt2];
                qq += 2; tt2 += 56;                   // 256 = 2*100 + 56
                if (tt2 >= Tn) { tt2 -= Tn; qq += 1; }
            }
        }
        {   // costT write (transpose via ctile; coalesced rows)
            float* tdst = cbw + q0;
            if (nq == QT) {
                for (int flat = tid; flat < QT * Tn; flat += 256) {
                    int r = flat >> 5, c = flat & 31;
                    tdst[(size_t)r * Qn + c] = ctile[c][r];
                }
            } else {
                for (int flat = tid; flat < nq * Tn; flat += 256) {
                    int r = flat / nq, c = flat - r * nq;
                    tdst[(size_t)r * Qn + c] = ctile[c][r];
                }
            }
        }
        if (tid < Tn) {                   // running row-min (first-index ties)
            #pragma unroll 4
            for (int q = 0; q < nq; ++q) {
                float x = ctile[q][tid];
                if (x < rbv) { rbv = x; rbq = q0 + q; }
            }
        }
        __syncthreads();                  // ctile reads done before next tile
    }

    if (tid < Tn) { u_lds[tid + 1] = rbv; amin_lds[tid] = rbq; }
    __syncthreads();

    // ---- phase B: greedy assignment ----
    if (tid < Tn) {
        int j = amin_lds[tid];
        int old = atomicCAS(&p0_lds[j], 0, tid + 1);
        asg[tid] = (old == 0) ? 1 : 0;
    }
    __syncthreads();
    if (tid < Tn && !asg[tid]) {
        int s = atomicAdd(&nfree_s, 1);
        freelist[s] = tid;
    }
    __syncthreads();
    const int nfree = nfree_s;

    // ---- phase C: lazy-dual Dijkstra (wave 0 only; costT is L2-hot) ----
    const float* cb = cbw;
    if (wv == 0 && nfree > 0) {
        const int cbase = lane << 4;          // columns cbase..cbase+15
        float v_r[16], dist_r[16], rc[16];
        int   p_r[16];
        #pragma unroll
        for (int k = 0; k < 16; ++k) v_r[k] = 0.0f;

#define LOADROW(dst, row1)                                                     \
        {                                                                      \
            const float* rp = cb + (size_t)((row1) - 1) * Qn;                  \
            if (cbase + 16 <= Qn) {                                            \
                _Pragma("unroll")                                              \
                for (int w4 = 0; w4 < 4; ++w4) {                               \
                    float4 f = *(const float4*)(rp + cbase + 4 * w4);          \
                    dst[4*w4+0] = f.x; dst[4*w4+1] = f.y;                      \
                    dst[4*w4+2] = f.z; dst[4*w4+3] = f.w;                      \
                }                                                              \
            } else {                                                           \
                _Pragma("unroll")                                              \
                for (int k = 0; k < 16; ++k)                                   \
                    dst[k] = (cbase + k < Qn) ? rp[cbase + k] : 3.0e38f;       \
            }                                                                  \
        }

        #pragma unroll 1
        for (int s = 0; s < nfree; ++s) {
            const int ri = freelist[s];       // uniform LDS read

            {   // refresh owner mirror (p constant during the search)
                const int4* pp = (const int4*)(p0_lds + cbase);
                int4 a = pp[0], bb = pp[1], cc4 = pp[2], dd4 = pp[3];
                p_r[0]=a.x;  p_r[1]=a.y;  p_r[2]=a.z;  p_r[3]=a.w;
                p_r[4]=bb.x; p_r[5]=bb.y; p_r[6]=bb.z; p_r[7]=bb.w;
                p_r[8]=cc4.x; p_r[9]=cc4.y; p_r[10]=cc4.z; p_r[11]=cc4.w;
                p_r[12]=dd4.x; p_r[13]=dd4.y; p_r[14]=dd4.z; p_r[15]=dd4.w;
            }
            #pragma unroll
            for (int k = 0; k < 16; ++k) dist_r[k] = 3.0e38f;
            unsigned um = 0;                  // scanned bits (per-lane slots)
            int   i0   = ri + 1;
            float d0   = 0.0f;
            int   jenc = 0;                   // parent col enc (+1; 0=root)
            int   sink0 = -1;
            float dstar = 0.0f;

            LOADROW(rc, i0);
            float ui0 = u_lds[i0];

            for (int it = 0; it < Tn + 2; ++it) {
                const float sft = d0 - ui0;
                float m[16];
                #pragma unroll
                for (int k = 0; k < 16; ++k) {
                    const int c = cbase + k;
                    const bool excl = (c >= Qn) || ((um >> k) & 1u);
                    float cand = sft + rc[k] - v_r[k];
                    if (!excl && cand < dist_r[k]) {
                        dist_r[k] = cand;
                        way_lds[(k << 6) | lane] = jenc;
                    }
                    m[k] = excl ? 3.0e38f : dist_r[k];
                }
                // per-lane min: fminf tree, depth 4
                float a01 = fminf(m[0], m[1]),   a23 = fminf(m[2], m[3]);
                float a45 = fminf(m[4], m[5]),   a67 = fminf(m[6], m[7]);
                float a89 = fminf(m[8], m[9]),   aAB = fminf(m[10], m[11]);
                float aCD = fminf(m[12], m[13]), aEF = fminf(m[14], m[15]);
                float bv = fminf(fminf(fminf(a01, a23), fminf(a45, a67)),
                                 fminf(fminf(a89, aAB), fminf(aCD, aEF)));

                unsigned gk = wave_min_u32(fkey(bv));
                const float delta = unfkey(gk);   // bit-exact: no shuffle

                int pk = 0;
                #pragma unroll
                for (int k = 0; k < 16; ++k)
                    if (m[k] == delta) pk = (cbase + k + 1) | (p_r[k] << 12);
                unsigned long long bal = __ballot(pk != 0);
                int src = __ffsll(bal) - 1;
                pk = __shfl(pk, src);
                const int bestj = (pk & 0xFFF) - 1;
                const int bp    = pk >> 12;

                if (bp == 0) { sink0 = bestj; dstar = delta; break; }

                if ((bestj >> 4) == lane) um |= 1u << (bestj & 15);
                LOADROW(rc, bp);              // gates next scan; issue first
                ui0 = u_lds[bp];
                d0 = delta; jenc = bestj + 1;
            }

            // dual updates (once per search)
            if (lane == 0) u_lds[ri + 1] += dstar;
            #pragma unroll
            for (int k = 0; k < 16; ++k) {
                if ((um >> k) & 1u) {
                    float dd = dstar - dist_r[k];
                    v_r[k] -= dd;             // v only decreases: stays <= 0
                    u_lds[p_r[k]] += dd;
                }
            }

            // augment along parent pointers
            if (lane == 0 && sink0 >= 0) {
                int jj = sink0;
                while (true) {
                    int w = way_lds[((jj & 15) << 6) | (jj >> 4)];
                    if (w == 0) { p0_lds[jj] = ri + 1; break; }
                    p0_lds[jj] = p0_lds[w - 1];
                    jj = w - 1;
                }
            }
            __threadfence_block();
        }
#undef LOADROW
    }
    __syncthreads();

    // ---- output indices ----
    for (int c = tid; c < Qn; c += 256) {
        int r = p0_lds[c];
        if (r) qarr[r - 1] = c;
    }
    __syncthreads();

    float* out_row = out + (size_t)Bq * Qn * Tn + (size_t)b * Tn;
    float* out_col = out_row + (size_t)Bq * Tn;
    for (int i = tid; i < Tn; i += 256) {
        int qi = qarr[i];
        int rank = 0;
        for (int jj = 0; jj < Tn; ++jj) rank += (qarr[jj] < qi) ? 1 : 0;
        out_row[rank] = (float)qi;   // row_ind: sorted query indices
        out_col[rank] = (float)i;    // col_ind: matched target indices
    }
}

// ---------------- Fallback: cost-only kernel (R14, costT/tilemin null) ------
__global__ __launch_bounds__(256) void cost_fused_kernel(
        const float* __restrict__ logits,
        const float* __restrict__ pred_bbox,
        const int*   __restrict__ tgt_labels,
        const float* __restrict__ tgt_bbox,
        float* __restrict__ cost)
{
    const int b   = blockIdx.y;
    const int q0  = blockIdx.x * QT;
    const int nq  = (q0 + QT <= Qn) ? QT : (Qn - q0);
    const int tid = threadIdx.x;

    __shared__ float prob[QT * Cn];
    __shared__ float pb_s[QT][4];
    __shared__ float tb_s[Tn][4];
    __shared__ int   lab_s[Tn];
    __shared__ float ctile[QT][Tn + 1];

    {
        const float4* src4 = (const float4*)(logits + ((size_t)b * Qn + q0) * Cn);
        float4* dst4 = (float4*)prob;
        const int n4 = nq * Cn / 4;
        for (int i = tid; i < n4; i += 256) dst4[i] = src4[i];
    }
    if (tid < nq)
        *(float4*)pb_s[tid] = *(const float4*)(pred_bbox + ((size_t)b * Qn + q0 + tid) * 4);
    if (tid < Tn) {
        *(float4*)tb_s[tid] = *(const float4*)(tgt_bbox + ((size_t)b * Tn + tid) * 4);
        lab_s[tid] = tgt_labels[b * Tn + tid];
    }
    __syncthreads();

    const int g = tid >> 3, l8 = tid & 7;
    if (g < nq) {
        float mx = -3.0e38f;
        for (int c = l8; c < Cn; c += 8) mx = fmaxf(mx, prob[g * Cn + c]);
        mx = fmaxf(mx, __shfl_xor(mx, 1));
        mx = fmaxf(mx, __shfl_xor(mx, 2));
        mx = fmaxf(mx, __shfl_xor(mx, 4));
        float s = 0.0f;
        for (int c = l8; c < Cn; c += 8) {
            float e = expf(prob[g * Cn + c] - mx);
            prob[g * Cn + c] = e;
            s += e;
        }
        s += __shfl_xor(s, 1);
        s += __shfl_xor(s, 2);
        s += __shfl_xor(s, 4);
        float inv = 1.0f / s;
        for (int c = l8; c < Cn; c += 8) prob[g * Cn + c] *= inv;
    }
    __syncthreads();

    if (g < nq) {
        const float pcx = pb_s[g][0], pcy = pb_s[g][1],
                    pw  = pb_s[g][2], ph  = pb_s[g][3];
        const float px1 = pcx - 0.5f * pw, py1 = pcy - 0.5f * ph;
        const float px2 = pcx + 0.5f * pw, py2 = pcy + 0.5f * ph;
        const float a1  = (px2 - px1) * (py2 - py1);
        const float* probg = prob + g * Cn;

        #pragma unroll
        for (int t = 0; t < 13; ++t) {
            const int tt = l8 + 8 * t;
            if (tt < Tn) {
                float4 tb = *(const float4*)tb_s[tt];
                const float tcx = tb.x, tcy = tb.y, tw = tb.z, th = tb.w;

                float cclass = -probg[lab_s[tt]];
                float cbbox  = fabsf(pcx - tcx) + fabsf(pcy - tcy)
                             + fabsf(pw - tw)  + fabsf(ph - th);

                float tx1 = tcx - 0.5f * tw, ty1 = tcy - 0.5f * th;
                float tx2 = tcx + 0.5f * tw, ty2 = tcy + 0.5f * th;

                float a2 = (tx2 - tx1) * (ty2 - ty1);
                float iw = fmaxf(fminf(px2, tx2) - fmaxf(px1, tx1), 0.0f);
                float ih = fmaxf(fminf(py2, ty2) - fmaxf(py1, ty1), 0.0f);
                float inter = iw * ih;
                float uni = a1 + a2 - inter;
                float iou = inter / uni;
                float ew = fmaxf(fmaxf(px2, tx2) - fminf(px1, tx1), 0.0f);
                float eh = fmaxf(fmaxf(py2, ty2) - fminf(py1, ty1), 0.0f);
                float ae = ew * eh;
                ctile[g][tt] = cbbox + cclass - (iou - (ae - uni) / ae);
            }
        }
    }
    __syncthreads();

    {
        float* cdst = cost + (size_t)b * Qn * Tn + (size_t)q0 * Tn;
        int qq = tid / Tn, tt = tid - qq * Tn;
        const int total = nq * Tn;
        for (int e = tid; e < total; e += 256) {
            cdst[e] = ctile[qq][tt];
            qq += 2; tt += 56;
            if (tt >= Tn) { tt -= Tn; qq += 1; }
        }
    }
}

// ---------------- Fallback JV (R4 verbatim, strided reads, no ws) ----------
__global__ __launch_bounds__(256) void jv_compat_kernel(
        const float* __restrict__ cost,   // [B,Q,T]
        float* __restrict__ out)
{
    const int b    = blockIdx.x;
    const int tid  = threadIdx.x;
    const int lane = tid & 63;
    const int wv   = tid >> 6;
    const bool act = (tid < Qn / 4);

    __shared__ int   p_lds[Qn + 1];
    __shared__ int   way_lds[Qn + 1];
    __shared__ float u_lds[Tn + 1];
    __shared__ int   amin_lds[Tn];
    __shared__ unsigned char asg[Tn];
    __shared__ int   freelist[Tn];
    __shared__ int   nfree_s;
    __shared__ float redv[2][4];
    __shared__ int   redj[2][4];
    __shared__ int   qarr[Tn];

    for (int j = tid; j <= Qn; j += 256) p_lds[j] = 0;
    if (tid == 0) nfree_s = 0;
    __syncthreads();

    const float* cb = cost + (size_t)b * Qn * Tn;

    for (int r = wv; r < Tn; r += 4) {
        float bv = 3.0e38f; int bj = 0x3fffffff;
        #pragma unroll
        for (int k = 0; k < 15; ++k) {
            int c = lane + 64 * k;
            if (c < Qn) {
                float x = cb[(size_t)c * Tn + r];
                if (x < bv) { bv = x; bj = c; }
            }
        }
        #pragma unroll
        for (int off = 1; off < 64; off <<= 1) {
            float ov = __shfl_xor(bv, off);
            int   oj = __shfl_xor(bj, off);
            if (ov < bv || (ov == bv && oj < bj)) { bv = ov; bj = oj; }
        }
        if (lane == 0) { u_lds[r + 1] = bv; amin_lds[r] = bj; }
    }
    __syncthreads();

    if (tid < Tn) {
        int j = amin_lds[tid];
        int old = atomicCAS(&p_lds[j + 1], 0, tid + 1);
        asg[tid] = (old == 0) ? 1 : 0;
    }
    __syncthreads();
    if (tid < Tn && !asg[tid]) {
        int s = atomicAdd(&nfree_s, 1);
        freelist[s] = tid;
    }
    __syncthreads();
    const int nfree = nfree_s;

    const int cbase = 4 * tid;
    float varr[4] = {0.0f, 0.0f, 0.0f, 0.0f};

    for (int s = 0; s < nfree; ++s) {
        const int ri = freelist[s];
        float minv[4] = {INFN, INFN, INFN, INFN};
        unsigned um = 0;
        int i0 = ri + 1, j0 = 0;
        if (tid == 0) p_lds[0] = i0;

        float c0v = 0, c1v = 0, c2v = 0, c3v = 0;
        if (act) {
            const float* cp = cb + (i0 - 1);
            c0v = cp[(size_t)cbase * Tn];       c1v = cp[(size_t)(cbase + 1) * Tn];
            c2v = cp[(size_t)(cbase + 2) * Tn]; c3v = cp[(size_t)(cbase + 3) * Tn];
        }
        float ui0 = u_lds[i0];

        for (int it = 0; it < Tn + 2; ++it) {
            if (j0 > 0 && act) {
                int cc = j0 - 1;
                if ((cc >> 2) == tid) um |= 1u << (cc & 3);
            }
            float bv = 3.0e9f; int bj = 0x3fffffff;
            if (act) {
                float crr[4] = {c0v, c1v, c2v, c3v};
                #pragma unroll
                for (int k = 0; k < 4; ++k) {
                    if (!((um >> k) & 1u)) {
                        float cur = crr[k] - ui0 - varr[k];
                        if (cur < minv[k]) { minv[k] = cur; way_lds[cbase + k + 1] = j0; }
                        if (minv[k] < bv) { bv = minv[k]; bj = cbase + k + 1; }
                    }
                }
            }
            #pragma unroll
            for (int off = 1; off < 64; off <<= 1) {
                float ov = __shfl_xor(bv, off);
                int   oj = __shfl_xor(bj, off);
                if (ov < bv || (ov == bv && oj < bj)) { bv = ov; bj = oj; }
            }
            const int par = it & 1;
            if (lane == 0) { redv[par][wv] = bv; redj[par][wv] = bj; }
            __syncthreads();
            float delta = redv[par][0]; int bestj = redj[par][0];
            #pragma unroll
            for (int w = 1; w < 4; ++w) {
                float ov = redv[par][w]; int oj = redj[par][w];
                if (ov < delta || (ov == delta && oj < bestj)) { delta = ov; bestj = oj; }
            }
            const int bp = p_lds[bestj];

            float ui_n = 0.0f, n0 = 0, n1 = 0, n2 = 0, n3 = 0;
            if (bp != 0) {
                if (act) {
                    const float* cp = cb + (bp - 1);
                    n0 = cp[(size_t)cbase * Tn];       n1 = cp[(size_t)(cbase + 1) * Tn];
                    n2 = cp[(size_t)(cbase + 2) * Tn]; n3 = cp[(size_t)(cbase + 3) * Tn];
                }
                ui_n = u_lds[bp];
            }

            if (tid == 0) u_lds[ri + 1] += delta;
            if (act) {
                #pragma unroll
                for (int k = 0; k < 4; ++k) {
                    if ((um >> k) & 1u) {
                        varr[k] -= delta;
                        u_lds[p_lds[cbase + k + 1]] += delta;
                    } else {
                        minv[k] -= delta;
                    }
                }
            }
            j0 = bestj;
            if (bp == 0) break;
            i0 = bp; ui0 = ui_n;
            c0v = n0; c1v = n1; c2v = n2; c3v = n3;
        }

        if (tid == 0) {
            int jj = j0;
            while (jj != 0) { int j1 = way_lds[jj]; p_lds[jj] = p_lds[j1]; jj = j1; }
        }
        __syncthreads();
    }

    for (int j = tid + 1; j <= Qn; j += 256) {
        int r = p_lds[j];
        if (r) qarr[r - 1] = j - 1;
    }
    __syncthreads();

    float* out_row = out + (size_t)Bq * Qn * Tn + (size_t)b * Tn;
    float* out_col = out_row + (size_t)Bq * Tn;
    for (int i = tid; i < Tn; i += 256) {
        int qi = qarr[i];
        int rank = 0;
        for (int jj = 0; jj < Tn; ++jj) rank += (qarr[jj] < qi) ? 1 : 0;
        out_row[rank] = (float)qi;
        out_col[rank] = (float)i;
    }
}

extern "C" void kernel_launch(void* const* d_in, const int* in_sizes, int n_in,
                              void* d_out, int out_size, void* d_ws, size_t ws_size,
                              hipStream_t stream) {
    const float* logits     = (const float*)d_in[0];
    const float* pred_bbox  = (const float*)d_in[1];
    const int*   tgt_labels = (const int*)d_in[2];
    const float* tgt_bbox   = (const float*)d_in[3];
    float* out = (float*)d_out;

    const size_t needT = (size_t)Bq * Qn * Tn * sizeof(float);   // 23.04 MB

    if (ws_size >= needT) {
        float* costT = (float*)d_ws;
        hipLaunchKernelGGL(fused_kernel, dim3(Bq), dim3(256), 0, stream,
                           logits, pred_bbox, tgt_labels, tgt_bbox, out, costT);
    } else {
        hipLaunchKernelGGL(cost_fused_kernel, dim3(NQT, Bq), dim3(256), 0, stream,
                           logits, pred_bbox, tgt_labels, tgt_bbox, out);
        hipLaunchKernelGGL(jv_compat_kernel, dim3(Bq), dim3(256), 0, stream,
                           out, out);
    }
}

// Round 17
// 93.307 us; speedup vs baseline: 2.9992x; 2.9992x over previous
//
#include <hip/hip_runtime.h>
#include <cmath>

#define Bq 64
#define Qn 900
#define Tn 100
#define Cn 92
#define INFN 1e9f
#define QT 32         // queries per cost tile (27KB LDS -> 5-6 blk/CU)
#define NQT 29        // ceil(900/32)

// ---- monotonic float<->uint key (bit-exact involution pair) ----
__device__ inline unsigned fkey(float x) {
    unsigned u = __float_as_uint(x);
    return (u & 0x80000000u) ? ~u : (u | 0x80000000u);
}
__device__ inline float unfkey(unsigned k) {
    unsigned u = (k & 0x80000000u) ? (k & 0x7FFFFFFFu) : ~k;
    return __uint_as_float(u);
}

// ---- wave64 min-reduce via DPP (rocPRIM pattern), broadcast from lane 63 ----
__device__ inline unsigned wave_min_u32(unsigned x) {
    unsigned t;
#define DPPSTEP(ctrl)                                                          \
    t = (unsigned)__builtin_amdgcn_update_dpp((int)0xFFFFFFFF, (int)x, ctrl,   \
                                              0xF, 0xF, false);                \
    x = (t < x) ? t : x;
    DPPSTEP(0x111)   // row_shr:1
    DPPSTEP(0x112)   // row_shr:2
    DPPSTEP(0x114)   // row_shr:4
    DPPSTEP(0x118)   // row_shr:8
    DPPSTEP(0x142)   // row_bcast:15
    DPPSTEP(0x143)   // row_bcast:31
#undef DPPSTEP
    return (unsigned)__builtin_amdgcn_readlane((int)x, 63);
}

// ---------------- Kernel A: fused cost + transpose + per-tile row minima ----
// R14 cost kernel (verified 94.0 total): QT=32, 8 lanes/query, float4 staging,
// flat coalesced cost write. Per-entry fp order identical to reference.
__global__ __launch_bounds__(256) void cost_fused_kernel(
        const float* __restrict__ logits,      // [B,Q,C]
        const float* __restrict__ pred_bbox,   // [B,Q,4]
        const int*   __restrict__ tgt_labels,  // [B,T]
        const float* __restrict__ tgt_bbox,    // [B,T,4]
        float* __restrict__ cost,              // [B,Q,T]
        float* __restrict__ costT,             // [B,T,Q] (may be null)
        unsigned long long* __restrict__ tilemin) // [B,NQT,T] packed (may be null)
{
    const int b   = blockIdx.y;
    const int q0  = blockIdx.x * QT;
    const int nq  = (q0 + QT <= Qn) ? QT : (Qn - q0);   // 32, or 4 on last tile
    const int tid = threadIdx.x;

    __shared__ float prob[QT * Cn];
    __shared__ float pb_s[QT][4];
    __shared__ float tb_s[Tn][4];
    __shared__ int   lab_s[Tn];
    __shared__ float ctile[QT][Tn + 1];

    {
        const float4* src4 = (const float4*)(logits + ((size_t)b * Qn + q0) * Cn);
        float4* dst4 = (float4*)prob;
        const int n4 = nq * Cn / 4;                  // Cn=92 -> divisible by 4
        for (int i = tid; i < n4; i += 256) dst4[i] = src4[i];
    }
    if (tid < nq)
        *(float4*)pb_s[tid] = *(const float4*)(pred_bbox + ((size_t)b * Qn + q0 + tid) * 4);
    if (tid < Tn) {
        *(float4*)tb_s[tid] = *(const float4*)(tgt_bbox + ((size_t)b * Tn + tid) * 4);
        lab_s[tid] = tgt_labels[b * Tn + tid];
    }
    __syncthreads();

    // softmax per query: 8 lanes per query
    const int g = tid >> 3, l8 = tid & 7;
    if (g < nq) {
        float mx = -3.0e38f;
        for (int c = l8; c < Cn; c += 8) mx = fmaxf(mx, prob[g * Cn + c]);
        mx = fmaxf(mx, __shfl_xor(mx, 1));
        mx = fmaxf(mx, __shfl_xor(mx, 2));
        mx = fmaxf(mx, __shfl_xor(mx, 4));
        float s = 0.0f;
        for (int c = l8; c < Cn; c += 8) {
            float e = expf(prob[g * Cn + c] - mx);
            prob[g * Cn + c] = e;
            s += e;
        }
        s += __shfl_xor(s, 1);
        s += __shfl_xor(s, 2);
        s += __shfl_xor(s, 4);
        float inv = 1.0f / s;
        for (int c = l8; c < Cn; c += 8) prob[g * Cn + c] *= inv;
    }
    __syncthreads();

    if (g < nq) {
        const float pcx = pb_s[g][0], pcy = pb_s[g][1],
                    pw  = pb_s[g][2], ph  = pb_s[g][3];
        const float px1 = pcx - 0.5f * pw, py1 = pcy - 0.5f * ph;
        const float px2 = pcx + 0.5f * pw, py2 = pcy + 0.5f * ph;
        const float a1  = (px2 - px1) * (py2 - py1);
        const float* probg = prob + g * Cn;

        #pragma unroll
        for (int t = 0; t < 13; ++t) {
            const int tt = l8 + 8 * t;
            if (tt < Tn) {
                float4 tb = *(const float4*)tb_s[tt];     // ds_read_b128
                const float tcx = tb.x, tcy = tb.y, tw = tb.z, th = tb.w;

                float cclass = -probg[lab_s[tt]];
                float cbbox  = fabsf(pcx - tcx) + fabsf(pcy - tcy)
                             + fabsf(pw - tw)  + fabsf(ph - th);

                float tx1 = tcx - 0.5f * tw, ty1 = tcy - 0.5f * th;
                float tx2 = tcx + 0.5f * tw, ty2 = tcy + 0.5f * th;

                float a2 = (tx2 - tx1) * (ty2 - ty1);
                float iw = fmaxf(fminf(px2, tx2) - fmaxf(px1, tx1), 0.0f);
                float ih = fmaxf(fminf(py2, ty2) - fmaxf(py1, ty1), 0.0f);
                float inter = iw * ih;
                float uni = a1 + a2 - inter;
                float iou = inter / uni;
                float ew = fmaxf(fmaxf(px2, tx2) - fminf(px1, tx1), 0.0f);
                float eh = fmaxf(fmaxf(py2, ty2) - fminf(py1, ty1), 0.0f);
                float ae = ew * eh;
                ctile[g][tt] = cbbox + cclass - (iou - (ae - uni) / ae);
            }
        }
    }
    __syncthreads();

    // flat, fully-coalesced cost write from ctile (incremental q/tt: no div)
    {
        float* cdst = cost + (size_t)b * Qn * Tn + (size_t)q0 * Tn;
        int qq = tid / Tn, tt = tid - qq * Tn;       // one div per thread
        const int total = nq * Tn;
        for (int e = tid; e < total; e += 256) {
            cdst[e] = ctile[qq][tt];
            qq += 2; tt += 56;                        // advance by 256 = 2*100+56
            if (tt >= Tn) { tt -= Tn; qq += 1; }
        }
    }

    if (costT) {
        float* tdst = costT + (size_t)b * Qn * Tn + q0;
        if (nq == QT) {
            for (int flat = tid; flat < QT * Tn; flat += 256) {
                int r = flat >> 5, c = flat & 31;     // QT=32
                tdst[(size_t)r * Qn + c] = ctile[c][r];
            }
        } else {
            for (int flat = tid; flat < nq * Tn; flat += 256) {
                int r = flat / nq, c = flat - r * nq;
                tdst[(size_t)r * Qn + c] = ctile[c][r];
            }
        }
    }
    if (tilemin && tid < Tn) {
        float bvv = 3.0e38f; int bq = 0;
        for (int q = 0; q < nq; ++q) {
            float x = ctile[q][tid];
            if (x < bvv) { bvv = x; bq = q; }
        }
        tilemin[((size_t)b * NQT + blockIdx.x) * Tn + tid] =
            ((unsigned long long)fkey(bvv) << 32) | (unsigned)(q0 + bq);
    }
}

// ---------------- Kernel B: JV — greedy init + lazy-dual Dijkstra (R12/R13) --
// VERBATIM R13 jv (measured 61.6 µs): NO setprio (R14's setprio was -2.6µs).
// Phase A: row minima (tilemin). Phase B: greedy argmin assignment (atomicCAS).
// Phase C (wave 0): lazy-dual Dijkstra; v starts 0, only decreases (v_j <= 0:
// rectangular dual feasibility — R9 lesson). fminf-tree + packed-shuffle
// reduce (R12). Waves 1-3 warm L2 concurrently (R10; serializing = -20µs R11).
template<bool TM>
__global__ __launch_bounds__(256) void jv_kernel(
        const float* __restrict__ costT,             // [B,T,Q]
        const unsigned long long* __restrict__ tilemin, // [B,NQT,T] or null
        float* __restrict__ out)
{
    const int b    = blockIdx.x;
    const int tid  = threadIdx.x;
    const int lane = tid & 63;
    const int wv   = tid >> 6;

    __shared__ int   p0_lds[1024];       // owner of 0-based col (0=free); padded
    __shared__ int   way_lds[1024];      // swizzled: col c at (c&15)<<6 | c>>4
    __shared__ float u_lds[Tn + 1];
    __shared__ int   amin_lds[Tn];
    __shared__ unsigned char asg[Tn];
    __shared__ int   freelist[Tn];
    __shared__ int   nfree_s;
    __shared__ int   qarr[Tn];

    for (int j = tid; j < 1024; j += 256) p0_lds[j] = 0;
    if (tid == 0) nfree_s = 0;
    __syncthreads();

    const float* cb = costT + (size_t)b * Qn * Tn;

    // ---- phase A: row minima ----
    if (TM) {
        if (tid < Tn) {
            unsigned long long best = ~0ull;
            for (int t = 0; t < NQT; ++t) {
                unsigned long long v = tilemin[((size_t)b * NQT + t) * Tn + tid];
                if (v < best) best = v;
            }
            u_lds[tid + 1] = unfkey((unsigned)(best >> 32));
            amin_lds[tid]  = (int)(best & 0xFFFFFFFFu);
        }
    } else {
        for (int r = wv; r < Tn; r += 4) {
            float bv = 3.0e38f; int bj = 0x3fffffff;
            #pragma unroll
            for (int k = 0; k < 15; ++k) {
                int c = lane + 64 * k;
                if (c < Qn) {
                    float x = cb[(size_t)r * Qn + c];
                    if (x < bv) { bv = x; bj = c; }
                }
            }
            #pragma unroll
            for (int off = 1; off < 64; off <<= 1) {
                float ov = __shfl_xor(bv, off);
                int   oj = __shfl_xor(bj, off);
                if (ov < bv || (ov == bv && oj < bj)) { bv = ov; bj = oj; }
            }
            if (lane == 0) { u_lds[r + 1] = bv; amin_lds[r] = bj; }
        }
    }
    __syncthreads();

    // ---- phase B: greedy assignment ----
    if (tid < Tn) {
        int j = amin_lds[tid];
        int old = atomicCAS(&p0_lds[j], 0, tid + 1);
        asg[tid] = (old == 0) ? 1 : 0;
    }
    __syncthreads();
    if (tid < Tn && !asg[tid]) {
        int s = atomicAdd(&nfree_s, 1);
        freelist[s] = tid;
    }
    __syncthreads();
    const int nfree = nfree_s;

    // ---- phase C: lazy-dual Dijkstra (wave 0) + concurrent L2 warm (1-3) ----
    if (wv == 0 && nfree > 0) {
        const int cbase = lane << 4;          // columns cbase..cbase+15
        float v_r[16], dist_r[16], rc[16];
        int   p_r[16];
        #pragma unroll
        for (int k = 0; k < 16; ++k) v_r[k] = 0.0f;

#define LOADROW(dst, row1)                                                     \
        {                                                                      \
            const float* rp = cb + (size_t)((row1) - 1) * Qn;                  \
            if (cbase + 16 <= Qn) {                                            \
                _Pragma("unroll")                                              \
                for (int w4 = 0; w4 < 4; ++w4) {                               \
                    float4 f = *(const float4*)(rp + cbase + 4 * w4);          \
                    dst[4*w4+0] = f.x; dst[4*w4+1] = f.y;                      \
                    dst[4*w4+2] = f.z; dst[4*w4+3] = f.w;                      \
                }                                                              \
            } else {                                                           \
                _Pragma("unroll")                                              \
                for (int k = 0; k < 16; ++k)                                   \
                    dst[k] = (cbase + k < Qn) ? rp[cbase + k] : 3.0e38f;       \
            }                                                                  \
        }

        #pragma unroll 1
        for (int s = 0; s < nfree; ++s) {
            const int ri = freelist[s];       // uniform LDS read

            {   // refresh owner mirror (p constant during the search)
                const int4* pp = (const int4*)(p0_lds + cbase);
                int4 a = pp[0], bb = pp[1], cc4 = pp[2], dd4 = pp[3];
                p_r[0]=a.x;  p_r[1]=a.y;  p_r[2]=a.z;  p_r[3]=a.w;
                p_r[4]=bb.x; p_r[5]=bb.y; p_r[6]=bb.z; p_r[7]=bb.w;
                p_r[8]=cc4.x; p_r[9]=cc4.y; p_r[10]=cc4.z; p_r[11]=cc4.w;
                p_r[12]=dd4.x; p_r[13]=dd4.y; p_r[14]=dd4.z; p_r[15]=dd4.w;
            }
            #pragma unroll
            for (int k = 0; k < 16; ++k) dist_r[k] = 3.0e38f;
            unsigned um = 0;                  // scanned bits (per-lane slots)
            int   i0   = ri + 1;              // current row, 1-based
            float d0   = 0.0f;                // dist of current row
            int   jenc = 0;                   // parent col enc (+1; 0=root)
            int   sink0 = -1;
            float dstar = 0.0f;

            LOADROW(rc, i0);
            float ui0 = u_lds[i0];

            for (int it = 0; it < Tn + 2; ++it) {
                const float sft = d0 - ui0;
                float m[16];
                #pragma unroll
                for (int k = 0; k < 16; ++k) {
                    const int c = cbase + k;
                    const bool excl = (c >= Qn) || ((um >> k) & 1u);
                    float cand = sft + rc[k] - v_r[k];
                    if (!excl && cand < dist_r[k]) {
                        dist_r[k] = cand;
                        way_lds[(k << 6) | lane] = jenc;
                    }
                    m[k] = excl ? 3.0e38f : dist_r[k];
                }
                // per-lane min: fminf tree, depth 4 (no index tracking)
                float a01 = fminf(m[0], m[1]),   a23 = fminf(m[2], m[3]);
                float a45 = fminf(m[4], m[5]),   a67 = fminf(m[6], m[7]);
                float a89 = fminf(m[8], m[9]),   aAB = fminf(m[10], m[11]);
                float aCD = fminf(m[12], m[13]), aEF = fminf(m[14], m[15]);
                float bv = fminf(fminf(fminf(a01, a23), fminf(a45, a67)),
                                 fminf(fminf(a89, aAB), fminf(aCD, aEF)));

                unsigned gk = wave_min_u32(fkey(bv));
                const float delta = unfkey(gk);   // bit-exact: no shuffle

                // locate the winning slot by value; pack (col+1)|owner<<12
                int pk = 0;
                #pragma unroll
                for (int k = 0; k < 16; ++k)
                    if (m[k] == delta) pk = (cbase + k + 1) | (p_r[k] << 12);
                unsigned long long bal = __ballot(pk != 0);
                int src = __ffsll(bal) - 1;
                pk = __shfl(pk, src);
                const int bestj = (pk & 0xFFF) - 1;   // 0-based column
                const int bp    = pk >> 12;           // owner row (0=free)

                if (bp == 0) { sink0 = bestj; dstar = delta; break; }

                if ((bestj >> 4) == lane) um |= 1u << (bestj & 15);
                LOADROW(rc, bp);              // gates next scan; issue first
                ui0 = u_lds[bp];
                d0 = delta; jenc = bestj + 1;
            }

            // dual updates (once per search)
            if (lane == 0) u_lds[ri + 1] += dstar;
            #pragma unroll
            for (int k = 0; k < 16; ++k) {
                if ((um >> k) & 1u) {
                    float dd = dstar - dist_r[k];
                    v_r[k] -= dd;             // v only decreases: stays <= 0
                    u_lds[p_r[k]] += dd;      // distinct tree rows: no races
                }
            }

            // augment along parent pointers
            if (lane == 0 && sink0 >= 0) {
                int jj = sink0;
                while (true) {
                    int w = way_lds[((jj & 15) << 6) | (jj >> 4)];
                    if (w == 0) { p0_lds[jj] = ri + 1; break; }
                    p0_lds[jj] = p0_lds[w - 1];
                    jj = w - 1;
                }
            }
            __threadfence_block();
        }
#undef LOADROW
    } else if (nfree > 0 && tid >= 64) {
        // waves 1-3: warm L2 with this batch's costT slab concurrently
        float acc = 0.0f;
        for (int ofs = (tid - 64) * 16; ofs < Tn * Qn; ofs += 192 * 16)
            acc += cb[ofs];
        asm volatile("" :: "v"(acc));      // keep loads alive (no DCE)
    }
    __syncthreads();

    // ---- output ----
    for (int c = tid; c < Qn; c += 256) {
        int r = p0_lds[c];
        if (r) qarr[r - 1] = c;
    }
    __syncthreads();

    float* out_row = out + (size_t)Bq * Qn * Tn + (size_t)b * Tn;
    float* out_col = out_row + (size_t)Bq * Tn;
    for (int i = tid; i < Tn; i += 256) {
        int qi = qarr[i];
        int rank = 0;
        for (int jj = 0; jj < Tn; ++jj) rank += (qarr[jj] < qi) ? 1 : 0;
        out_row[rank] = (float)qi;   // row_ind: sorted query indices
        out_col[rank] = (float)i;    // col_ind: matched target indices
    }
}

// ---------------- Fallback JV (R4 verbatim, strided reads, no ws) ----------
__global__ __launch_bounds__(256) void jv_compat_kernel(
        const float* __restrict__ cost,   // [B,Q,T]
        float* __restrict__ out)
{
    const int b    = blockIdx.x;
    const int tid  = threadIdx.x;
    const int lane = tid & 63;
    const int wv   = tid >> 6;
    const bool act = (tid < Qn / 4);

    __shared__ int   p_lds[Qn + 1];
    __shared__ int   way_lds[Qn + 1];
    __shared__ float u_lds[Tn + 1];
    __shared__ int   amin_lds[Tn];
    __shared__ unsigned char asg[Tn];
    __shared__ int   freelist[Tn];
    __shared__ int   nfree_s;
    __shared__ float redv[2][4];
    __shared__ int   redj[2][4];
    __shared__ int   qarr[Tn];

    for (int j = tid; j <= Qn; j += 256) p_lds[j] = 0;
    if (tid == 0) nfree_s = 0;
    __syncthreads();

    const float* cb = cost + (size_t)b * Qn * Tn;

    for (int r = wv; r < Tn; r += 4) {
        float bv = 3.0e38f; int bj = 0x3fffffff;
        #pragma unroll
        for (int k = 0; k < 15; ++k) {
            int c = lane + 64 * k;
            if (c < Qn) {
                float x = cb[(size_t)c * Tn + r];
                if (x < bv) { bv = x; bj = c; }
            }
        }
        #pragma unroll
        for (int off = 1; off < 64; off <<= 1) {
            float ov = __shfl_xor(bv, off);
            int   oj = __shfl_xor(bj, off);
            if (ov < bv || (ov == bv && oj < bj)) { bv = ov; bj = oj; }
        }
        if (lane == 0) { u_lds[r + 1] = bv; amin_lds[r] = bj; }
    }
    __syncthreads();

    if (tid < Tn) {
        int j = amin_lds[tid];
        int old = atomicCAS(&p_lds[j + 1], 0, tid + 1);
        asg[tid] = (old == 0) ? 1 : 0;
    }
    __syncthreads();
    if (tid < Tn && !asg[tid]) {
        int s = atomicAdd(&nfree_s, 1);
        freelist[s] = tid;
    }
    __syncthreads();
    const int nfree = nfree_s;

    const int cbase = 4 * tid;
    float varr[4] = {0.0f, 0.0f, 0.0f, 0.0f};

    for (int s = 0; s < nfree; ++s) {
        const int ri = freelist[s];
        float minv[4] = {INFN, INFN, INFN, INFN};
        unsigned um = 0;
        int i0 = ri + 1, j0 = 0;
        if (tid == 0) p_lds[0] = i0;

        float c0v = 0, c1v = 0, c2v = 0, c3v = 0;
        if (act) {
            const float* cp = cb + (i0 - 1);
            c0v = cp[(size_t)cbase * Tn];       c1v = cp[(size_t)(cbase + 1) * Tn];
            c2v = cp[(size_t)(cbase + 2) * Tn]; c3v = cp[(size_t)(cbase + 3) * Tn];
        }
        float ui0 = u_lds[i0];

        for (int it = 0; it < Tn + 2; ++it) {
            if (j0 > 0 && act) {
                int cc = j0 - 1;
                if ((cc >> 2) == tid) um |= 1u << (cc & 3);
            }
            float bv = 3.0e9f; int bj = 0x3fffffff;
            if (act) {
                float crr[4] = {c0v, c1v, c2v, c3v};
                #pragma unroll
                for (int k = 0; k < 4; ++k) {
                    if (!((um >> k) & 1u)) {
                        float cur = crr[k] - ui0 - varr[k];
                        if (cur < minv[k]) { minv[k] = cur; way_lds[cbase + k + 1] = j0; }
                        if (minv[k] < bv) { bv = minv[k]; bj = cbase + k + 1; }
                    }
                }
            }
            #pragma unroll
            for (int off = 1; off < 64; off <<= 1) {
                float ov = __shfl_xor(bv, off);
                int   oj = __shfl_xor(bj, off);
                if (ov < bv || (ov == bv && oj < bj)) { bv = ov; bj = oj; }
            }
            const int par = it & 1;
            if (lane == 0) { redv[par][wv] = bv; redj[par][wv] = bj; }
            __syncthreads();
            float delta = redv[par][0]; int bestj = redj[par][0];
            #pragma unroll
            for (int w = 1; w < 4; ++w) {
                float ov = redv[par][w]; int oj = redj[par][w];
                if (ov < delta || (ov == delta && oj < bestj)) { delta = ov; bestj = oj; }
            }
            const int bp = p_lds[bestj];

            float ui_n = 0.0f, n0 = 0, n1 = 0, n2 = 0, n3 = 0;
            if (bp != 0) {
                if (act) {
                    const float* cp = cb + (bp - 1);
                    n0 = cp[(size_t)cbase * Tn];       n1 = cp[(size_t)(cbase + 1) * Tn];
                    n2 = cp[(size_t)(cbase + 2) * Tn]; n3 = cp[(size_t)(cbase + 3) * Tn];
                }
                ui_n = u_lds[bp];
            }

            if (tid == 0) u_lds[ri + 1] += delta;
            if (act) {
                #pragma unroll
                for (int k = 0; k < 4; ++k) {
                    if ((um >> k) & 1u) {
                        varr[k] -= delta;
                        u_lds[p_lds[cbase + k + 1]] += delta;
                    } else {
                        minv[k] -= delta;
                    }
                }
            }
            j0 = bestj;
            if (bp == 0) break;
            i0 = bp; ui0 = ui_n;
            c0v = n0; c1v = n1; c2v = n2; c3v = n3;
        }

        if (tid == 0) {
            int jj = j0;
            while (jj != 0) { int j1 = way_lds[jj]; p_lds[jj] = p_lds[j1]; jj = j1; }
        }
        __syncthreads();
    }

    for (int j = tid + 1; j <= Qn; j += 256) {
        int r = p_lds[j];
        if (r) qarr[r - 1] = j - 1;
    }
    __syncthreads();

    float* out_row = out + (size_t)Bq * Qn * Tn + (size_t)b * Tn;
    float* out_col = out_row + (size_t)Bq * Tn;
    for (int i = tid; i < Tn; i += 256) {
        int qi = qarr[i];
        int rank = 0;
        for (int jj = 0; jj < Tn; ++jj) rank += (qarr[jj] < qi) ? 1 : 0;
        out_row[rank] = (float)qi;
        out_col[rank] = (float)i;
    }
}

extern "C" void kernel_launch(void* const* d_in, const int* in_sizes, int n_in,
                              void* d_out, int out_size, void* d_ws, size_t ws_size,
                              hipStream_t stream) {
    const float* logits     = (const float*)d_in[0];
    const float* pred_bbox  = (const float*)d_in[1];
    const int*   tgt_labels = (const int*)d_in[2];
    const float* tgt_bbox   = (const float*)d_in[3];
    float* out = (float*)d_out;

    const size_t needT  = (size_t)Bq * Qn * Tn * sizeof(float);        // 23.04 MB
    const size_t needTM = needT + (size_t)Bq * NQT * Tn * 8 + 4096;    // +1.49 MB

    if (ws_size >= needTM) {
        float* costT = (float*)d_ws;
        unsigned long long* tilemin = (unsigned long long*)((char*)d_ws + needT);
        hipLaunchKernelGGL(cost_fused_kernel, dim3(NQT, Bq), dim3(256), 0, stream,
                           logits, pred_bbox, tgt_labels, tgt_bbox, out, costT, tilemin);
        hipLaunchKernelGGL((jv_kernel<true>), dim3(Bq), dim3(256), 0, stream,
                           costT, tilemin, out);
    } else if (ws_size >= needT) {
        float* costT = (float*)d_ws;
        hipLaunchKernelGGL(cost_fused_kernel, dim3(NQT, Bq), dim3(256), 0, stream,
                           logits, pred_bbox, tgt_labels, tgt_bbox, out, costT,
                           (unsigned long long*)nullptr);
        hipLaunchKernelGGL((jv_kernel<false>), dim3(Bq), dim3(256), 0, stream,
                           costT, (const unsigned long long*)nullptr, out);
    } else {
        hipLaunchKernelGGL(cost_fused_kernel, dim3(NQT, Bq), dim3(256), 0, stream,
                           logits, pred_bbox, tgt_labels, tgt_bbox, out, (float*)nullptr,
                           (unsigned long long*)nullptr);
        hipLaunchKernelGGL(jv_compat_kernel, dim3(Bq), dim3(256), 0, stream,
                           out, out);
    }
}